// Round 9
// baseline (156.210 us; speedup 1.0000x reference)
//
#include <hip/hip_runtime.h>
#include <cmath>

#define C 128     // in/out channels

typedef __bf16 bf16x8 __attribute__((ext_vector_type(8)));
typedef float  f32x4  __attribute__((ext_vector_type(4)));
typedef unsigned short u16x8 __attribute__((ext_vector_type(8)));

// fp32 -> bf16 bits, round-to-nearest-even
static __device__ __forceinline__ unsigned short f2b(float f) {
    unsigned int u = __builtin_bit_cast(unsigned int, f);
    u += 0x7FFFu + ((u >> 16) & 1u);
    return (unsigned short)(u >> 16);
}
// bf16 bits -> fp32
static __device__ __forceinline__ float b2f(unsigned short u) {
    return __builtin_bit_cast(float, (unsigned int)u << 16);
}

// ---------------------------------------------------------------------------
// Zero the counts array (HIP's fill kernel is launch-latency overhead).
// ---------------------------------------------------------------------------
__global__ __launch_bounds__(256)
void sage_zero(int4* __restrict__ p, int n4) {
    int i = blockIdx.x * blockDim.x + threadIdx.x;
    if (i < n4) p[i] = make_int4(0, 0, 0, 0);
}

// ---------------------------------------------------------------------------
// Prep kernel, role by block range:
//  [0, CB)   : in-degree counts, 8 edges/thread (int atomics)
//  [CB,+16)  : pack B = [Wl | Wr] (K=128 x N=256) into MFMA-fragment order:
//              frag f = kt*16 + c (kt k-tile 0..3, c n-tile 0..15), lane l,
//              elem j: k = kt*32 + (l>>4)*8 + j, n = c*16 + (l&15).
//              B(k,n) = n<128 ? Wl[n][k] : Wr[n-128][k].
// ---------------------------------------------------------------------------
__global__ __launch_bounds__(256)
void sage_prep(const int* __restrict__ ei, const float* __restrict__ Wl,
               const float* __restrict__ Wr, int* __restrict__ counts,
               unsigned short* __restrict__ wp, int E, int CB) {
    int bid = blockIdx.x;
    int t = threadIdx.x;
    if (bid < CB) {
        int e = (bid * 256 + t) * 8;
        if (e + 7 < E) {
            int4 d0 = *(const int4*)(ei + E + e);
            int4 d1 = *(const int4*)(ei + E + e + 4);
            atomicAdd(&counts[d0.x], 1);
            atomicAdd(&counts[d0.y], 1);
            atomicAdd(&counts[d0.z], 1);
            atomicAdd(&counts[d0.w], 1);
            atomicAdd(&counts[d1.x], 1);
            atomicAdd(&counts[d1.y], 1);
            atomicAdd(&counts[d1.z], 1);
            atomicAdd(&counts[d1.w], 1);
        } else {
            for (; e < E; ++e) atomicAdd(&counts[ei[E + e]], 1);
        }
    } else {
        int s = (bid - CB) * 256 + t;        // 0..4095
        int f = s >> 6, l = s & 63;
        int kt = f >> 4, c = f & 15;
        int g = l >> 4;
        int n = c * 16 + (l & 15);
        const float* src = (n < C) ? (Wl + (size_t)n * C)
                                   : (Wr + (size_t)(n - C) * C);
        u16x8 o;
#pragma unroll
        for (int j = 0; j < 8; ++j) {
            int k = kt * 32 + g * 8 + j;
            o[j] = f2b(src[k]);
        }
        *(u16x8*)(wp + (size_t)s * 8) = o;
    }
}

// ---------------------------------------------------------------------------
// CSR build, step 2: single-block exclusive scan -> cursor.
// After sage_fill, cursor[i] == inclusive scan (end offset of node i).
// ---------------------------------------------------------------------------
__global__ __launch_bounds__(1024)
void sage_scan(const int* __restrict__ counts, int* __restrict__ cursor, int N) {
    __shared__ int part[1024];
    const int t = threadIdx.x;
    const int CH = 64;                    // 1024 * 64 = 65536 >= N
    const int lo = t * CH;

    int s = 0;
    if (lo + CH <= N) {
        const int4* c4 = (const int4*)(counts + lo);
#pragma unroll
        for (int i = 0; i < CH / 4; ++i) {
            int4 v = c4[i];
            s += v.x + v.y + v.z + v.w;
        }
    } else {
        for (int i = lo; i < N; ++i) s += counts[i];
    }
    part[t] = s;
    __syncthreads();
    for (int off = 1; off < 1024; off <<= 1) {
        int v = (t >= off) ? part[t - off] : 0;
        __syncthreads();
        part[t] += v;
        __syncthreads();
    }
    int run = (t == 0) ? 0 : part[t - 1];

    if (lo + CH <= N) {
        const int4* c4 = (const int4*)(counts + lo);
        int4* u4 = (int4*)(cursor + lo);
#pragma unroll
        for (int i = 0; i < CH / 4; ++i) {
            int4 v = c4[i];
            int4 o;
            o.x = run; run += v.x;
            o.y = run; run += v.y;
            o.z = run; run += v.z;
            o.w = run; run += v.w;
            u4[i] = o;
        }
    } else {
        for (int i = lo; i < N; ++i) {
            cursor[i] = run;
            run += counts[i];
        }
    }
}

// ---------------------------------------------------------------------------
// CSR build, step 3: scatter src ids; cursor becomes inclusive scan.
// ---------------------------------------------------------------------------
__global__ __launch_bounds__(256)
void sage_fill(const int* __restrict__ ei, int* __restrict__ cursor,
               int* __restrict__ csr, int E) {
    int i = blockIdx.x * blockDim.x + threadIdx.x;
    int e = i * 4;
    if (e + 3 < E) {
        int4 sv = *(const int4*)(ei + e);
        int4 dv = *(const int4*)(ei + E + e);
        csr[atomicAdd(&cursor[dv.x], 1)] = sv.x;
        csr[atomicAdd(&cursor[dv.y], 1)] = sv.y;
        csr[atomicAdd(&cursor[dv.z], 1)] = sv.z;
        csr[atomicAdd(&cursor[dv.w], 1)] = sv.w;
    } else {
        for (; e < E; ++e) {
            int pos = atomicAdd(&cursor[ei[E + e]], 1);
            csr[pos] = ei[e];
        }
    }
}

// ---------------------------------------------------------------------------
// MFMA GEMM (linearity trick): y_l = x@Wl^T (bf16), y_r = x@Wr^T + b (bf16).
// Block = 256 thr = 4 waves = 16 nodes; K = 128 (4 k-tiles); 16 n-tiles.
// Wave w owns n-tiles w*4..w*4+3 (waves 0,1 -> y_l cols, waves 2,3 -> y_r).
// A built in-register from fp32 x (f2b), same k-slot convention as B pack.
// ---------------------------------------------------------------------------
__global__ __launch_bounds__(256)
void sage_gemm(const float* __restrict__ x, const unsigned short* __restrict__ wp,
               const float* __restrict__ bias, unsigned short* __restrict__ yl,
               unsigned short* __restrict__ yr, int N) {
    int t = threadIdx.x;
    int w = t >> 6, l = t & 63;
    int base = blockIdx.x * 16;
    int g = l >> 4;
    int node = base + (l & 15);
    if (node >= N) node = N - 1;          // clamp (N%16==0 normally)

    const float4* xv = (const float4*)(x + (size_t)node * C);
    const bf16x8* B = (const bf16x8*)wp;

    f32x4 acc0 = {0.f, 0.f, 0.f, 0.f};
    f32x4 acc1 = {0.f, 0.f, 0.f, 0.f};
    f32x4 acc2 = {0.f, 0.f, 0.f, 0.f};
    f32x4 acc3 = {0.f, 0.f, 0.f, 0.f};

#pragma unroll
    for (int kt = 0; kt < 4; ++kt) {
        float4 xa = xv[kt * 8 + g * 2];
        float4 xc = xv[kt * 8 + g * 2 + 1];
        u16x8 ab;
        ab[0] = f2b(xa.x); ab[1] = f2b(xa.y);
        ab[2] = f2b(xa.z); ab[3] = f2b(xa.w);
        ab[4] = f2b(xc.x); ab[5] = f2b(xc.y);
        ab[6] = f2b(xc.z); ab[7] = f2b(xc.w);
        bf16x8 af = __builtin_bit_cast(bf16x8, ab);
        int c = w * 4;
        bf16x8 b0 = B[(size_t)(kt * 16 + c + 0) * 64 + l];
        bf16x8 b1 = B[(size_t)(kt * 16 + c + 1) * 64 + l];
        bf16x8 b2 = B[(size_t)(kt * 16 + c + 2) * 64 + l];
        bf16x8 b3 = B[(size_t)(kt * 16 + c + 3) * 64 + l];
        acc0 = __builtin_amdgcn_mfma_f32_16x16x32_bf16(af, b0, acc0, 0, 0, 0);
        acc1 = __builtin_amdgcn_mfma_f32_16x16x32_bf16(af, b1, acc1, 0, 0, 0);
        acc2 = __builtin_amdgcn_mfma_f32_16x16x32_bf16(af, b2, acc2, 0, 0, 0);
        acc3 = __builtin_amdgcn_mfma_f32_16x16x32_bf16(af, b3, acc3, 0, 0, 0);
    }

    // Epilogue. C/D (verified m89): col = l&15, row = g*4 + reg.
#pragma unroll
    for (int i = 0; i < 4; ++i) {
        f32x4 a = (i == 0) ? acc0 : (i == 1) ? acc1 : (i == 2) ? acc2 : acc3;
        int c = w * 4 + i;
        int n = c * 16 + (l & 15);
        if (w < 2) {
#pragma unroll
            for (int r = 0; r < 4; ++r) {
                int row = base + g * 4 + r;
                if (row < N) yl[(size_t)row * C + n] = f2b(a[r]);
            }
        } else {
            float bs = bias[n - C];
#pragma unroll
            for (int r = 0; r < 4; ++r) {
                int row = base + g * 4 + r;
                if (row < N) yr[(size_t)row * C + (n - C)] = f2b(a[r] + bs);
            }
        }
    }
}

// ---------------------------------------------------------------------------
// Final: out = mean_agg(y_l) + y_r -> log_softmax.  One wave per node, no
// LDS (full occupancy hides gather latency). Quarter-wave per neighbor row
// (16 lanes x 16 B = one 256 B bf16 row), 4-deep pipeline; cross-quarter
// shfl reduce; lanes 0-15 finish: 8 feats each, shfl-lsm, float4 writes.
// ---------------------------------------------------------------------------
__global__ __launch_bounds__(256)
void sage_final(const unsigned short* __restrict__ yl,
                const unsigned short* __restrict__ yr,
                const int* __restrict__ cursor, const int* __restrict__ csr,
                float* __restrict__ out, int N) {
    int wv = threadIdx.x >> 6;
    int node = blockIdx.x * 4 + wv;
    if (node >= N) return;
    int ln = threadIdx.x & 63;
    int q = ln >> 4;        // quarter: owns neighbor residues q (mod 4)
    int fl = ln & 15;       // 16B slot within the 256B row

    int p0 = (node == 0) ? 0 : cursor[node - 1];
    int p1 = cursor[node];
    int deg = p1 - p0;

    float a[8];
#pragma unroll
    for (int j = 0; j < 8; ++j) a[j] = 0.f;

    int p = p0 + q;
    for (; p + 12 < p1; p += 16) {
        int s0 = csr[p];
        int s1 = csr[p + 4];
        int s2 = csr[p + 8];
        int s3 = csr[p + 12];
        u16x8 v0 = *(const u16x8*)(yl + (size_t)s0 * C + fl * 8);
        u16x8 v1 = *(const u16x8*)(yl + (size_t)s1 * C + fl * 8);
        u16x8 v2 = *(const u16x8*)(yl + (size_t)s2 * C + fl * 8);
        u16x8 v3 = *(const u16x8*)(yl + (size_t)s3 * C + fl * 8);
#pragma unroll
        for (int j = 0; j < 8; ++j)
            a[j] += (b2f(v0[j]) + b2f(v1[j])) + (b2f(v2[j]) + b2f(v3[j]));
    }
    for (; p + 4 < p1; p += 8) {
        int s0 = csr[p];
        int s1 = csr[p + 4];
        u16x8 v0 = *(const u16x8*)(yl + (size_t)s0 * C + fl * 8);
        u16x8 v1 = *(const u16x8*)(yl + (size_t)s1 * C + fl * 8);
#pragma unroll
        for (int j = 0; j < 8; ++j) a[j] += b2f(v0[j]) + b2f(v1[j]);
    }
    if (p < p1) {
        int s0 = csr[p];
        u16x8 v0 = *(const u16x8*)(yl + (size_t)s0 * C + fl * 8);
#pragma unroll
        for (int j = 0; j < 8; ++j) a[j] += b2f(v0[j]);
    }

#pragma unroll
    for (int j = 0; j < 8; ++j) {
        a[j] += __shfl_xor(a[j], 16);
        a[j] += __shfl_xor(a[j], 32);
    }
    if (q != 0) return;

    // lanes 0..15: finish node. vals = mean + y_r (bias already inside).
    float inv = 1.0f / fmaxf((float)deg, 1.0f);
    u16x8 yv = *(const u16x8*)(yr + (size_t)node * C + fl * 8);
#pragma unroll
    for (int j = 0; j < 8; ++j) a[j] = a[j] * inv + b2f(yv[j]);

    float m = a[0];
#pragma unroll
    for (int j = 1; j < 8; ++j) m = fmaxf(m, a[j]);
#pragma unroll
    for (int off = 1; off < 16; off <<= 1)
        m = fmaxf(m, __shfl_xor(m, off));
    float s = 0.f;
#pragma unroll
    for (int j = 0; j < 8; ++j) s += expf(a[j] - m);
#pragma unroll
    for (int off = 1; off < 16; off <<= 1)
        s += __shfl_xor(s, off);
    float ls = m + logf(s);

    float4 o0, o1;
    o0.x = a[0] - ls; o0.y = a[1] - ls; o0.z = a[2] - ls; o0.w = a[3] - ls;
    o1.x = a[4] - ls; o1.y = a[5] - ls; o1.z = a[6] - ls; o1.w = a[7] - ls;
    float4* op = (float4*)(out + (size_t)node * C + fl * 8);
    op[0] = o0;
    op[1] = o1;
}

extern "C" void kernel_launch(void* const* d_in, const int* in_sizes, int n_in,
                              void* d_out, int out_size, void* d_ws, size_t ws_size,
                              hipStream_t stream) {
    const float* x  = (const float*)d_in[0];
    const int*   ei = (const int*)d_in[1];
    const float* Wl = (const float*)d_in[2];
    const float* Wr = (const float*)d_in[3];
    const float* b  = (const float*)d_in[4];
    float* out = (float*)d_out;

    const int N = in_sizes[0] / C;   // 50000
    const int E = in_sizes[1] / 2;   // 600000

    // ws layout (16B-aligned pieces): ~28.5 MB total
    int* counts = (int*)d_ws;                             // N
    int* cursor = counts + N;                             // N
    int* csr    = cursor + N;                             // E
    unsigned short* yl = (unsigned short*)(csr + E);      // N*C bf16
    unsigned short* yr = yl + (size_t)N * C;              // N*C bf16
    unsigned short* wp = yr + (size_t)N * C;              // 128*256 bf16 pack

    const int CB = (E + 2047) / 2048;        // count blocks (8 edges/thread)
    int eb4 = (E + 1023) / 1024;
    int n4 = (N + 3) / 4;

    sage_zero<<<(n4 + 255) / 256, 256, 0, stream>>>((int4*)counts, n4);
    sage_prep<<<CB + 16, 256, 0, stream>>>(ei, Wl, Wr, counts, wp, E, CB);
    sage_gemm<<<(N + 15) / 16, 256, 0, stream>>>(x, wp, b, yl, yr, N);
    sage_scan<<<1, 1024, 0, stream>>>(counts, cursor, N);
    sage_fill<<<eb4, 256, 0, stream>>>(ei, cursor, csr, E);
    sage_final<<<(N + 3) / 4, 256, 0, stream>>>(yl, yr, cursor, csr, out, N);
}